// Round 19
// baseline (2075.640 us; speedup 1.0000x reference)
//
#include <hip/hip_runtime.h>
#include <math.h>
#include <stdint.h>

#define NLAYER 6
#define DIMD 512
#define HEADS 8
#define HD 64
#define EXPERTS 8
#define SEQ 1024
#define NTOK 2048
#define FF 1024
#define VOCABN 50257
#define HROWS 50432  // 197*256 zero-padded head rows

typedef __bf16 bf16;
typedef __bf16 bf16x8 __attribute__((ext_vector_type(8)));
typedef __bf16 bf16x4 __attribute__((ext_vector_type(4)));
typedef float f32x4 __attribute__((ext_vector_type(4)));

__device__ __forceinline__ void gl_lds16(const void* g, void* l) {
  __builtin_amdgcn_global_load_lds(
      (const __attribute__((address_space(1))) void*)(uintptr_t)g,
      (__attribute__((address_space(3))) void*)(uintptr_t)l, 16, 0, 0);
}

// LDS element offset for (row, 16B-chunk), BK=32 tiles: XOR swizzle (2-way = free)
#define LDSW(row, kg) (((row) * 32) + ((((kg) ^ (((row) >> 1) & 3))) << 3))

// ====== multi-pass split-bf16 MFMA GEMM, counted-vmcnt pipeline ======
// 128x128 tile, BK=32, double-buffered LDS; steady-state s_waitcnt vmcnt(4)
// keeps one 4-load stage in flight across barriers (T3/T4).
// modes: 0:1p  3:2p(A2,Bexact)  5:3p(A2xB2)
// outmode: 0 normal; 2 qkv-split out: q->(Cb0,Cb1) k->(Cb2,E0) vt->(E1,E2)
__global__ __launch_bounds__(256) void k_mfma_gemm(
    const bf16* __restrict__ A0, const bf16* __restrict__ A1,
    const bf16* __restrict__ B0, const bf16* __restrict__ B1,
    float* __restrict__ Cf, bf16* __restrict__ Cb0, bf16* __restrict__ Cb1,
    bf16* __restrict__ Cb2, bf16* __restrict__ E0, bf16* __restrict__ E1,
    bf16* __restrict__ E2, int M, int N, int K,
    long sA, long sB, long sCf, long sCb,
    const float* __restrict__ colScale, int csStride,
    const float* __restrict__ bias, int biasStride,
    const float* __restrict__ residual, int act, int mode,
    const int* __restrict__ mLimit, const int* __restrict__ aperm,
    int outmode) {
  __shared__ __align__(16) bf16 As[2][128 * 32];
  __shared__ __align__(16) bf16 Bs[2][128 * 32];
  int tid = threadIdx.x;
  int z = blockIdx.z;
  // bijective XCD-aware swizzle (m204)
  int nwg = gridDim.x * gridDim.y;
  int flat = blockIdx.y * gridDim.x + blockIdx.x;
  int qq = nwg >> 3, rr = nwg & 7;
  int xcd = flat & 7, ii = flat >> 3;
  int swz = (xcd < rr ? xcd * (qq + 1) : rr * (qq + 1) + (xcd - rr) * qq) + ii;
  int m0 = (swz % gridDim.x) * 128, n0 = (swz / gridDim.x) * 128;
  if (mLimit && m0 >= mLimit[z]) return;
  int w = tid >> 6, lane = tid & 63;
  int wm = (w >> 1) * 64, wn = (w & 1) * 64;
  int r15 = lane & 15, kg = lane >> 4;

  int pa[3] = {0, 0, 0}, pb[3] = {0, 0, 0};
  int np = 1;
  if (mode == 3) {
    np = 2; pa[1] = 1;
  } else if (mode == 5) {
    np = 3;
    pa[1] = 0; pb[1] = 1; pa[2] = 1; pb[2] = 0;
  }

  f32x4 acc[4][4] = {};
  int srow = tid >> 2;
  // global source chunk pre-swizzled so linear LDS dest == swizzled layout
  int scol = (((tid & 3) ^ ((tid >> 3) & 3))) << 3;
  long arow0, arow1;
  if (aperm) {
    arow0 = aperm[z * 2048 + m0 + srow];
    arow1 = aperm[z * 2048 + m0 + 64 + srow];
  } else {
    arow0 = m0 + srow;
    arow1 = m0 + 64 + srow;
  }
  const bf16* PA[2] = {A0, A1};
  const bf16* PB[2] = {B0, B1};

  // monotone staging state (stage() called exactly nIter times, in order)
  const int kIters = K / 32;
  const int nIter = np * kIters;
  int sp = 0, staged = 0;
  const bf16 *sa0, *sa1, *sb0, *sb1;
  auto resetPassPtrs = [&](int p) {
    const bf16* Az = PA[pa[p]] + (long)z * sA;
    const bf16* Bz = PB[pb[p]] + (long)z * sB;
    sa0 = Az + arow0 * K + scol;
    sa1 = Az + arow1 * K + scol;
    sb0 = Bz + (long)(n0 + srow) * K + scol;
    sb1 = Bz + (long)(n0 + 64 + srow) * K + scol;
  };
  resetPassPtrs(0);
  auto stage = [&](int buf) {
    gl_lds16(sa0, &As[buf][tid * 8]);
    gl_lds16(sa1, &As[buf][2048 + tid * 8]);
    gl_lds16(sb0, &Bs[buf][tid * 8]);
    gl_lds16(sb1, &Bs[buf][2048 + tid * 8]);
    sa0 += 32; sa1 += 32; sb0 += 32; sb1 += 32;
    if (++staged == kIters) {
      staged = 0;
      if (++sp < np) resetPassPtrs(sp);
    }
  };
  auto compute = [&](int buf) {
    bf16x8 af[4], bfr[4];
#pragma unroll
    for (int mi = 0; mi < 4; ++mi) {
      int rowA = wm + mi * 16 + r15;
      af[mi] = *(const bf16x8*)&As[buf][LDSW(rowA, kg)];
    }
#pragma unroll
    for (int ni = 0; ni < 4; ++ni) {
      int rowB = wn + ni * 16 + r15;
      bfr[ni] = *(const bf16x8*)&Bs[buf][LDSW(rowB, kg)];
    }
#pragma unroll
    for (int mi = 0; mi < 4; ++mi)
#pragma unroll
      for (int ni = 0; ni < 4; ++ni)
        acc[mi][ni] = __builtin_amdgcn_mfma_f32_16x16x32_bf16(
            af[mi], bfr[ni], acc[mi][ni], 0, 0, 0);
  };

  stage(0);
  stage(1);
#pragma unroll 1
  for (int it = 0; it < nIter - 2; ++it) {
    asm volatile("s_waitcnt vmcnt(4)" ::: "memory");  // stage it landed
    __builtin_amdgcn_s_barrier();                     // publish cross-wave
    __builtin_amdgcn_sched_barrier(0);
    compute(it & 1);
    __builtin_amdgcn_s_barrier();  // readers done with buf (it&1)
    stage(it & 1);                 // restage freed buffer; stays in flight
  }
  asm volatile("s_waitcnt vmcnt(4)" ::: "memory");
  __builtin_amdgcn_s_barrier();
  __builtin_amdgcn_sched_barrier(0);
  compute(nIter & 1);
  asm volatile("s_waitcnt vmcnt(0)" ::: "memory");
  __builtin_amdgcn_s_barrier();
  __builtin_amdgcn_sched_barrier(0);
  compute((nIter - 1) & 1);

  // C/D layout: col=lane&15, row=(lane>>4)*4+reg  [m89]
#pragma unroll
  for (int mi = 0; mi < 4; ++mi) {
    int rbase = m0 + wm + mi * 16 + kg * 4;
#pragma unroll
    for (int ni = 0; ni < 4; ++ni) {
      int col = n0 + wn + ni * 16 + r15;
      if (col >= N) continue;
      float scl = colScale ? colScale[z * csStride + col] : 1.f;
      float bv = bias ? bias[z * biasStride + col] : 0.f;
#pragma unroll
      for (int reg = 0; reg < 4; ++reg) {
        int row = rbase + reg;
        float v = acc[mi][ni][reg] * scl + bv;
        if (act) v = 0.5f * v * (1.f + erff(v * 0.70710678118654752f));
        if (residual) v += residual[(long)row * N + col];
        if (outmode == 2) {
          int b = row >> 10, qt = row & 1023;
          if (n0 < 512) {  // Q, pre-scaled by 0.125 (exact)
            float qv = v * 0.125f;
            int h = col >> 6, d = col & 63;
            long dst = ((long)(b * 8 + h)) * ((long)SEQ * HD) +
                       (long)qt * HD + d;
            bf16 h0 = (bf16)qv;
            Cb0[dst] = h0;
            Cb1[dst] = (bf16)(qv - (float)h0);
          } else if (n0 < 1024) {  // K
            int c2 = col - 512;
            int h = c2 >> 6, d = c2 & 63;
            long dst = ((long)(b * 8 + h)) * ((long)SEQ * HD) +
                       (long)qt * HD + d;
            bf16 h0 = (bf16)v;
            Cb2[dst] = h0;
            E0[dst] = (bf16)(v - (float)h0);
          } else {  // V^T: [bh][d=64][k]
            int c2 = col - 1024;
            int h = c2 >> 6, d = c2 & 63;
            long dst = ((long)(b * 8 + h)) * ((long)HD * SEQ) +
                       (long)d * SEQ + qt;
            bf16 h0 = (bf16)v;
            E1[dst] = h0;
            E2[dst] = (bf16)(v - (float)h0);
          }
          continue;
        }
        if (Cf) Cf[z * sCf + (long)row * N + col] = v;
        if (Cb0) {
          long cib = z * sCb + (long)row * N + col;
          bf16 h0 = (bf16)v;
          Cb0[cib] = h0;
          if (Cb1) {
            float r = v - (float)h0;
            Cb1[cib] = (bf16)r;
          }
        }
      }
    }
  }
}

// ====== fused SINGLE-PASS flash attention, QBLK=32, 2-wave blocks ======
// block = (32 q-rows, bh); 2 waves, wave = 16 q-rows; grid 512 = 2 blk/CU
// (40 KB LDS) so two barrier-independent blocks co-reside per CU and hide
// each other's K/V staging drains. Per-q-row math identical to QBLK=64.
__global__ __launch_bounds__(128) void k_fattn(
    const bf16* __restrict__ q0b, const bf16* __restrict__ q1b,
    const bf16* __restrict__ k0b, const bf16* __restrict__ k1b,
    const bf16* __restrict__ vt0, const bf16* __restrict__ vt1,
    bf16* __restrict__ at0, bf16* __restrict__ at1) {
  __shared__ __align__(16) bf16 Ks[2][64 * 64];
  __shared__ __align__(16) bf16 Vs[2][64 * 64];
  __shared__ __align__(16) bf16 Ps[2][32 * 64];
  int tid = threadIdx.x;  // 0..127
  int bh = blockIdx.y;
  int q0 = blockIdx.x * 32;
  int w = tid >> 6, lane = tid & 63;  // w in {0,1}
  int r15 = lane & 15, kg = lane >> 4;
  const long bhQK = (long)bh * SEQ * HD;
  const long bhV = (long)bh * HD * SEQ;

  // Q fragments in registers (Q already scaled by 0.125 at qkv epilogue)
  bf16x8 qa0[2], qa1[2];
  {
    long qoff = bhQK + (long)(q0 + w * 16 + r15) * HD;
#pragma unroll
    for (int ks = 0; ks < 2; ++ks) {
      qa0[ks] = *(const bf16x8*)&q0b[qoff + ks * 32 + kg * 8];
      qa1[ks] = *(const bf16x8*)&q1b[qoff + ks * 32 + kg * 8];
    }
  }

  // stage K-tile (64x64, 2 splits) with pre-swizzled source (rule #21)
  auto stageK = [&](int kt) {
#pragma unroll
    for (int i = 0; i < 4; ++i) {
      int L = tid + i * 128;
      int row = L >> 3, pc = L & 7;
      int gc = pc ^ (row & 7);
      long gsrc = bhQK + (long)(kt * 64 + row) * HD + gc * 8;
      gl_lds16(k0b + gsrc, &Ks[0][L * 8]);
      gl_lds16(k1b + gsrc, &Ks[1][L * 8]);
    }
  };
  // stage V-tile (V^T 64 d-rows x 64 k-cols, 2 splits)
  auto stageV = [&](int kt) {
#pragma unroll
    for (int i = 0; i < 4; ++i) {
      int L = tid + i * 128;
      int row = L >> 3, pc = L & 7;
      int gc = pc ^ (row & 7);
      long gsrc = bhV + (long)row * SEQ + kt * 64 + gc * 8;
      gl_lds16(vt0 + gsrc, &Vs[0][L * 8]);
      gl_lds16(vt1 + gsrc, &Vs[1][L * 8]);
    }
  };
  // sf[kc]: k-cols kc*16+r15 (kc 0..3), q-rows kg*4+reg (C/D layout m89)
  auto computeS = [&](f32x4* sf) {
    __builtin_amdgcn_s_setprio(1);
#pragma unroll
    for (int kc = 0; kc < 4; ++kc) {
      f32x4 a = {};
      int rowB = kc * 16 + r15;
#pragma unroll
      for (int ks = 0; ks < 2; ++ks) {
        int pc = (ks * 4 + kg) ^ (rowB & 7);
        bf16x8 b0 = *(const bf16x8*)&Ks[0][rowB * 64 + pc * 8];
        bf16x8 b1 = *(const bf16x8*)&Ks[1][rowB * 64 + pc * 8];
        a = __builtin_amdgcn_mfma_f32_16x16x32_bf16(qa0[ks], b0, a, 0, 0, 0);
        a = __builtin_amdgcn_mfma_f32_16x16x32_bf16(qa0[ks], b1, a, 0, 0, 0);
        a = __builtin_amdgcn_mfma_f32_16x16x32_bf16(qa1[ks], b0, a, 0, 0, 0);
      }
      sf[kc] = a;
    }
    __builtin_amdgcn_s_setprio(0);
  };

  float m[4], l[4];
#pragma unroll
  for (int r = 0; r < 4; ++r) { m[r] = -1e30f; l[r] = 0.f; }
  f32x4 oacc[4] = {};

  for (int kt = 0; kt < SEQ / 64; ++kt) {
    stageK(kt);
    stageV(kt);
    __syncthreads();  // drains vmcnt: K,V ready
    f32x4 sf[4];
    computeS(sf);
    // online stats + rescale O; P = exp(S - m_new) (unnormalized)
#pragma unroll
    for (int r = 0; r < 4; ++r) {
      float tm = sf[0][r];
#pragma unroll
      for (int kc = 1; kc < 4; ++kc) tm = fmaxf(tm, sf[kc][r]);
      tm = fmaxf(tm, __shfl_xor(tm, 1));
      tm = fmaxf(tm, __shfl_xor(tm, 2));
      tm = fmaxf(tm, __shfl_xor(tm, 4));
      tm = fmaxf(tm, __shfl_xor(tm, 8));
      float mn = fmaxf(m[r], tm);
      float corr = __expf(m[r] - mn);
      float s = 0.f;
#pragma unroll
      for (int kc = 0; kc < 4; ++kc) {
        float p = __expf(sf[kc][r] - mn);
        sf[kc][r] = p;
        s += p;
      }
      s += __shfl_xor(s, 1);
      s += __shfl_xor(s, 2);
      s += __shfl_xor(s, 4);
      s += __shfl_xor(s, 8);
      l[r] = l[r] * corr + s;
      m[r] = mn;
#pragma unroll
      for (int dg = 0; dg < 4; ++dg) oacc[dg][r] *= corr;
    }
    // P -> 2-split bf16 into wave-private swizzled Ps rows (qrow 0..31)
#pragma unroll
    for (int kc = 0; kc < 4; ++kc) {
#pragma unroll
      for (int r = 0; r < 4; ++r) {
        float p = sf[kc][r];
        bf16 h0 = (bf16)p;
        bf16 h1 = (bf16)(p - (float)h0);
        int qrow = w * 16 + kg * 4 + r;
        int kcol = kc * 16 + r15;
        int pc = (kcol >> 3) ^ (qrow & 7);
        int addr = qrow * 64 + pc * 8 + (kcol & 7);
        Ps[0][addr] = h0;
        Ps[1][addr] = h1;
      }
    }
    // PV (Ps rows are wave-private: same-wave lgkmcnt ordering suffices)
    bf16x8 pa0[2], pa1[2];
    int rowP = w * 16 + r15;
#pragma unroll
    for (int ks = 0; ks < 2; ++ks) {
      int pc = (ks * 4 + kg) ^ (rowP & 7);
      pa0[ks] = *(const bf16x8*)&Ps[0][rowP * 64 + pc * 8];
      pa1[ks] = *(const bf16x8*)&Ps[1][rowP * 64 + pc * 8];
    }
    __builtin_amdgcn_s_setprio(1);
#pragma unroll
    for (int dg = 0; dg < 4; ++dg) {
      int rowV = dg * 16 + r15;
#pragma unroll
      for (int ks = 0; ks < 2; ++ks) {
        int pc = (ks * 4 + kg) ^ (rowV & 7);
        bf16x8 v0 = *(const bf16x8*)&Vs[0][rowV * 64 + pc * 8];
        bf16x8 v1 = *(const bf16x8*)&Vs[1][rowV * 64 + pc * 8];
        oacc[dg] = __builtin_amdgcn_mfma_f32_16x16x32_bf16(pa0[ks], v0,
                                                           oacc[dg], 0, 0, 0);
        oacc[dg] = __builtin_amdgcn_mfma_f32_16x16x32_bf16(pa0[ks], v1,
                                                           oacc[dg], 0, 0, 0);
        oacc[dg] = __builtin_amdgcn_mfma_f32_16x16x32_bf16(pa1[ks], v0,
                                                           oacc[dg], 0, 0, 0);
      }
    }
    __builtin_amdgcn_s_setprio(0);
    __syncthreads();  // all waves done reading Ks/Vs before restage
  }

  float invl[4];
#pragma unroll
  for (int r = 0; r < 4; ++r) invl[r] = 1.f / l[r];

  // epilogue: token-layout 2-split O
  int b = bh >> 3, h = bh & 7;
#pragma unroll
  for (int dg = 0; dg < 4; ++dg) {
#pragma unroll
    for (int r = 0; r < 4; ++r) {
      int qrow = q0 + w * 16 + kg * 4 + r;
      int d = dg * 16 + r15;
      long dst = ((long)(b * SEQ + qrow)) * DIMD + h * HD + d;
      float v = oacc[dg][r] * invl[r];
      bf16 h0 = (bf16)v;
      at0[dst] = h0;
      at1[dst] = (bf16)(v - (float)h0);
    }
  }
}

// ====== head GEMM: 256x256 tile, BK=64, 8 waves, counted-vmcnt pipeline ======
__global__ __launch_bounds__(512, 2) void k_hgemm(const bf16* __restrict__ A,
                                                  const bf16* __restrict__ Bt,
                                                  float* __restrict__ C,
                                                  int M, int N, int K) {
  __shared__ __align__(16) bf16 As[2][256 * 64];
  __shared__ __align__(16) bf16 Bs[2][256 * 64];
  int tid = threadIdx.x;
  int nwg = gridDim.x * gridDim.y;
  int flat = blockIdx.y * gridDim.x + blockIdx.x;
  int qq = nwg >> 3, rr = nwg & 7;
  int xcd = flat & 7, ii = flat >> 3;
  int swz = (xcd < rr ? xcd * (qq + 1) : rr * (qq + 1) + (xcd - rr) * qq) + ii;
  int m0 = (swz % gridDim.x) * 256, n0 = (swz / gridDim.x) * 256;
  int w = tid >> 6, lane = tid & 63;
  int wm = (w >> 2) * 128, wn = (w & 3) * 64;  // 2M x 4N waves
  int r15 = lane & 15, kg = lane >> 4;

  auto stage = [&](int buf, int kt) {
#pragma unroll
    for (int j = 0; j < 4; ++j) {
      int L = tid + j * 512;
      int row = L >> 3, pc = L & 7;
      int gc = pc ^ (row & 7);  // pre-swizzled source, linear LDS dest
      gl_lds16(A + (long)(m0 + row) * K + kt * 64 + gc * 8, &As[buf][L * 8]);
      gl_lds16(Bt + (long)(n0 + row) * K + kt * 64 + gc * 8, &Bs[buf][L * 8]);
    }
  };

  f32x4 acc[8][4] = {};
  auto compute = [&](int buf) {
#pragma unroll
    for (int ks = 0; ks < 2; ++ks) {
      bf16x8 af[8], bf_[4];
#pragma unroll
      for (int mi = 0; mi < 8; ++mi) {
        int row = wm + mi * 16 + r15;
        af[mi] = *(const bf16x8*)
            &As[buf][row * 64 + ((((ks * 4 + kg) ^ (row & 7))) << 3)];
      }
#pragma unroll
      for (int ni = 0; ni < 4; ++ni) {
        int row = wn + ni * 16 + r15;
        bf_[ni] = *(const bf16x8*)
            &Bs[buf][row * 64 + ((((ks * 4 + kg) ^ (row & 7))) << 3)];
      }
#pragma unroll
      for (int mi = 0; mi < 8; ++mi)
#pragma unroll
        for (int ni = 0; ni < 4; ++ni)
          acc[mi][ni] = __builtin_amdgcn_mfma_f32_16x16x32_bf16(
              af[mi], bf_[ni], acc[mi][ni], 0, 0, 0);
    }
  };

  stage(0, 0);
  stage(1, 1);
#pragma unroll 1
  for (int t = 0; t < 6; ++t) {
    asm volatile("s_waitcnt vmcnt(8)" ::: "memory");  // tile t landed
    __builtin_amdgcn_s_barrier();                     // publish cross-wave
    __builtin_amdgcn_sched_barrier(0);
    compute(t & 1);
    __builtin_amdgcn_s_barrier();  // all waves done reading buf (t&1)
    stage(t & 1, t + 2);           // restage freed buffer; stays in flight
  }
  asm volatile("s_waitcnt vmcnt(8)" ::: "memory");
  __builtin_amdgcn_s_barrier();
  __builtin_amdgcn_sched_barrier(0);
  compute(0);
  asm volatile("s_waitcnt vmcnt(0)" ::: "memory");
  __builtin_amdgcn_s_barrier();
  __builtin_amdgcn_sched_barrier(0);
  compute(1);

  // epilogue: C/D layout col=lane&15, row=(lane>>4)*4+reg  [m89]
#pragma unroll
  for (int mi = 0; mi < 8; ++mi) {
    int rbase = m0 + wm + mi * 16 + kg * 4;
#pragma unroll
    for (int ni = 0; ni < 4; ++ni) {
      int col = n0 + wn + ni * 16 + r15;
      if (col >= N) continue;
#pragma unroll
      for (int reg = 0; reg < 4; ++reg)
        C[(long)(rbase + reg) * N + col] = acc[mi][ni][reg];
    }
  }
}

// ---------------- helpers ----------------
__global__ __launch_bounds__(256) void k_embed(const int* __restrict__ ids,
                                               const float* __restrict__ E,
                                               float* __restrict__ xf,
                                               bf16* __restrict__ x0,
                                               bf16* __restrict__ x1) {
  int i = blockIdx.x * 256 + threadIdx.x;
  if (i >= NTOK * DIMD) return;
  int n = i >> 9, d = i & 511;
  float v = E[(long)ids[n] * DIMD + d];
  xf[i] = v;
  bf16 b0 = (bf16)v;
  x0[i] = b0;
  x1[i] = (bf16)(v - (float)b0);
}

// ALL-layer weight split: grid (512, NLAYER); qkv_w chunks then out_w chunks
__global__ __launch_bounds__(256) void k_prepw(const float* __restrict__ qkv_w,
                                               const float* __restrict__ out_w,
                                               bf16* __restrict__ qw0a,
                                               bf16* __restrict__ qw1a,
                                               bf16* __restrict__ ow0a,
                                               bf16* __restrict__ ow1a) {
  int l = blockIdx.y;
  const long n8q = (long)3 * DIMD * DIMD / 8;
  long i = (long)blockIdx.x * 256 + threadIdx.x;
  const float* s;
  bf16 *d0, *d1;
  long j;
  if (i < n8q) {
    s = qkv_w + (long)l * 3 * DIMD * DIMD;
    d0 = qw0a + (long)l * 3 * DIMD * DIMD;
    d1 = qw1a + (long)l * 3 * DIMD * DIMD;
    j = i;
  } else {
    s = out_w + (long)l * DIMD * DIMD;
    d0 = ow0a + (long)l * DIMD * DIMD;
    d1 = ow1a + (long)l * DIMD * DIMD;
    j = i - n8q;
  }
  const float4* s4 = (const float4*)s;
  float4 a = s4[2 * j], b = s4[2 * j + 1];
  float vv[8] = {a.x, a.y, a.z, a.w, b.x, b.y, b.z, b.w};
  bf16x8 o0, o1;
#pragma unroll
  for (int k = 0; k < 8; ++k) {
    float v = vv[k];
    bf16 h0 = (bf16)v;
    o0[k] = h0;
    o1[k] = (bf16)(v - (float)h0);
  }
  ((bf16x8*)d0)[j] = o0;
  ((bf16x8*)d1)[j] = o1;
}

__global__ __launch_bounds__(256) void k_headconv(const float* __restrict__ s,
                                                  bf16* __restrict__ d) {
  long i = (long)blockIdx.x * 256 + threadIdx.x;
  long n8 = (long)HROWS * DIMD / 8;
  if (i >= n8) return;
  long row = i / (DIMD / 8);
  bf16x8 o;
  if (row < VOCABN) {
    const float4* s4 = (const float4*)s;
    float4 a = s4[2 * i], b = s4[2 * i + 1];
    o[0] = (bf16)a.x; o[1] = (bf16)a.y; o[2] = (bf16)a.z; o[3] = (bf16)a.w;
    o[4] = (bf16)b.x; o[5] = (bf16)b.y; o[6] = (bf16)b.z; o[7] = (bf16)b.w;
  } else {
    o = (bf16x8)(bf16)0.f;
  }
  ((bf16x8*)d)[i] = o;
}

// router: top-2 expert ids + normalized weights per token
__global__ __launch_bounds__(64) void k_router(const float* __restrict__ x,
                                               const float* __restrict__ rw,
                                               const float* __restrict__ rb,
                                               int* __restrict__ top2,
                                               float* __restrict__ v2) {
  int n = blockIdx.x;
  int t = threadIdx.x;
  int e = t >> 3, part = t & 7;
  __shared__ float red[64];
  const float* xr = x + (long)n * DIMD;
  const float* wr = rw + (long)e * DIMD;
  float d = 0.f;
  int c0 = part * 64;
#pragma unroll
  for (int c = 0; c < 64; c += 4) {
    float4 xv = *(const float4*)(xr + c0 + c);
    float4 wv = *(const float4*)(wr + c0 + c);
    d += xv.x * wv.x + xv.y * wv.y + xv.z * wv.z + xv.w * wv.w;
  }
  red[t] = d;
  __syncthreads();
  if (t < 8) {
    float logit = rb[t];
    for (int pp = 0; pp < 8; ++pp) logit += red[t * 8 + pp];
    red[t] = logit;
  }
  __syncthreads();
  if (t == 0) {
    float p2[8];
    float m = -1e30f;
    for (int i = 0; i < 8; ++i) m = fmaxf(m, red[i]);
    float s = 0.f;
    for (int i = 0; i < 8; ++i) { p2[i] = expf(red[i] - m); s += p2[i]; }
    for (int i = 0; i < 8; ++i) p2[i] /= s;
    int i1 = 0;
    for (int i = 1; i < 8; ++i) if (p2[i] > p2[i1]) i1 = i;
    int i2 = (i1 == 0) ? 1 : 0;
    for (int i = 0; i < 8; ++i) {
      if (i == i1 || i == i2) continue;
      if (p2[i] > p2[i2]) i2 = i;
    }
    float sum = p2[i1] + p2[i2] + 1e-8f;
    top2[2 * n] = i1;
    top2[2 * n + 1] = i2;
    v2[2 * n] = p2[i1] / sum;
    v2[2 * n + 1] = p2[i2] / sum;
  }
}

// per-expert token lists, one-pass 8-elem/thread prefix scan (deterministic)
__global__ __launch_bounds__(256) void k_expcnt(const int* __restrict__ top2,
                                                int* __restrict__ perm,
                                                int* __restrict__ tokpos,
                                                int* __restrict__ cnt,
                                                bf16* __restrict__ zx0,
                                                bf16* __restrict__ zx1) {
  int e = blockIdx.x, t = threadIdx.x;
  if (e == 0) {
    for (int c = t; c < DIMD; c += 256) {
      zx0[c] = (bf16)0.f;
      zx1[c] = (bf16)0.f;
    }
  }
  __shared__ int sc[256];
  int fl[8];
  int f = 0;
#pragma unroll
  for (int j = 0; j < 8; ++j) {
    int n = t * 8 + j;
    int m = (top2[2 * n] == e || top2[2 * n + 1] == e) ? 1 : 0;
    fl[j] = m;
    f += m;
  }
  sc[t] = f;
  __syncthreads();
  for (int o = 1; o < 256; o <<= 1) {
    int v = (t >= o) ? sc[t - o] : 0;
    __syncthreads();
    sc[t] += v;
    __syncthreads();
  }
  int pos = sc[t] - f;  // exclusive prefix
#pragma unroll
  for (int j = 0; j < 8; ++j) {
    if (fl[j]) {
      int n = t * 8 + j;
      perm[e * 2048 + pos] = n;
      int jj = (top2[2 * n] == e) ? 0 : 1;
      tokpos[2 * n + jj] = e * 2048 + pos;
      ++pos;
    }
  }
  int total = sc[255];
  int cpad = (total + 127) & ~127;
  for (int i = total + t; i < cpad; i += 256) perm[e * 2048 + i] = 2048;
  if (t == 0) cnt[e] = total;
}

// ALL-layer BitNet quant: grid (12288, NLAYER); blocks [0,8192)=we1 rows
__global__ __launch_bounds__(256) void k_bitw2(const float* __restrict__ w1,
                                               const float* __restrict__ w2,
                                               bf16* __restrict__ we1qa,
                                               float* __restrict__ s1a,
                                               bf16* __restrict__ we2qa,
                                               float* __restrict__ s2a) {
  int l = blockIdx.y;
  int blk = blockIdx.x;
  int t = threadIdx.x;
  const float* wr;
  bf16* outr;
  float* sOut;
  int cols;
  if (blk < EXPERTS * FF) {
    cols = DIMD;
    wr = w1 + (long)l * EXPERTS * FF * DIMD + (long)blk * cols;
    outr = we1qa + (long)l * EXPERTS * FF * DIMD + (long)blk * cols;
    sOut = s1a + (long)l * EXPERTS * FF + blk;
  } else {
    int row = blk - EXPERTS * FF;
    cols = FF;
    wr = w2 + (long)l * EXPERTS * DIMD * FF + (long)row * cols;
    outr = we2qa + (long)l * EXPERTS * DIMD * FF + (long)row * cols;
    sOut = s2a + (long)l * EXPERTS * DIMD + row;
  }
  float acc = 0.f;
  for (int c = t; c < cols; c += 256) acc += fabsf(wr[c]);
  __shared__ float red[256];
  red[t] = acc;
  __syncthreads();
  for (int off = 128; off; off >>= 1) {
    if (t < off) red[t] += red[t + off];
    __syncthreads();
  }
  float scale = fmaxf(red[0] / (float)cols, 1e-5f);
  if (t == 0) *sOut = scale;
  for (int c = t; c < cols; c += 256) {
    float qv = rintf(wr[c] / scale);  // RNE, matches jnp.round
    qv = fmaxf(-1.f, fminf(1.f, qv));
    outr[c] = (bf16)qv;
  }
}

// combine top-2 experts (gathered f32 y), add residual, LN -> f32 + 2-split
__global__ __launch_bounds__(128) void k_lncomb(
    const float* __restrict__ yg, const int* __restrict__ tokpos,
    const float* __restrict__ v2, const float* __restrict__ xBf,
    const float* __restrict__ g, const float* __restrict__ b,
    float* __restrict__ xof, bf16* __restrict__ x0, bf16* __restrict__ x1) {
  int n = blockIdx.x;
  int t = threadIdx.x;
  __shared__ float red[128];
  long tp0 = tokpos[2 * n], tp1 = tokpos[2 * n + 1];
  float w0 = v2[2 * n], w1 = v2[2 * n + 1];
  const float* y0 = yg + tp0 * DIMD;
  const float* y1 = yg + tp1 * DIMD;
  float u[4];
  float s = 0.f;
#pragma unroll
  for (int i = 0; i < 4; ++i) {
    int d = t + i * 128;
    float v = xBf[(long)n * DIMD + d] + w0 * y0[d] + w1 * y1[d];
    u[i] = v;
    s += v;
  }
  red[t] = s;
  __syncthreads();
  for (int off = 64; off; off >>= 1) {
    if (t < off) red[t] += red[t + off];
    __syncthreads();
  }
  float mu = red[0] / (float)DIMD;
  __syncthreads();
  float var = 0.f;
#pragma unroll
  for (int i = 0; i < 4; ++i) {
    float d = u[i] - mu;
    var += d * d;
  }
  red[t] = var;
  __syncthreads();
  for (int off = 64; off; off >>= 1) {
    if (t < off) red[t] += red[t + off];
    __syncthreads();
  }
  float inv = 1.f / sqrtf(red[0] / (float)DIMD + 1e-5f);
#pragma unroll
  for (int i = 0; i < 4; ++i) {
    int c = t + i * 128;
    float v = (u[i] - mu) * inv * g[c] + b[c];
    long oi = (long)n * DIMD + c;
    xof[oi] = v;
    bf16 b0 = (bf16)v;
    x0[oi] = b0;
    x1[oi] = (bf16)(v - (float)b0);
  }
}

extern "C" void kernel_launch(void* const* d_in, const int* in_sizes, int n_in,
                              void* d_out, int out_size, void* d_ws, size_t ws_size,
                              hipStream_t stream) {
  const int* ids = (const int*)d_in[0];
  const float* embed = (const float*)d_in[1];
  const float* qkv_w = (const float*)d_in[2];
  const float* out_w = (const float*)d_in[3];
  const float* router_w = (const float*)d_in[4];
  const float* router_b = (const float*)d_in[5];
  const float* w1 = (const float*)d_in[6];
  const float* b1 = (const float*)d_in[7];
  const float* w2 = (const float*)d_in[8];
  const float* b2 = (const float*)d_in[9];
  const float* ln_g = (const float*)d_in[10];
  const float* ln_b = (const float*)d_in[11];
  const float* head_w = (const float*)d_in[12];
  float* out = (float*)d_out;

  char* base = (char*)d_ws;
  size_t off = 0;
  auto alloc = [&](size_t bytes) -> void* {
    void* p = base + off;
    off += (bytes + 255) & ~(size_t)255;
    return p;
  };
  const size_t ND = (size_t)NTOK * DIMD;
  float* xAf = (float*)alloc(ND * 4);
  float* xBf = (float*)alloc(ND * 4);
  int* top2 = (int*)alloc((size_t)NTOK * 2 * 4);
  float* v2 = (float*)alloc((size_t)NTOK * 2 * 4);
  int* perm = (int*)alloc((size_t)EXPERTS * 2048 * 4);
  int* tokpos = (int*)alloc((size_t)NTOK * 2 * 4);
  int* cntb = (int*)alloc(64);
  bf16* xA0 = (bf16*)alloc(ND * 2);
  bf16* xA1 = (bf16*)alloc(ND * 2);
  bf16* xB0 = (bf16*)alloc((ND + DIMD) * 2);  // +1 zero row (idx 2048)
  bf16* xB1 = (bf16*)alloc((ND + DIMD) * 2);
  bf16* at0 = (bf16*)alloc(ND * 2);
  bf16* at1 = (bf16*)alloc(ND * 2);
  bf16* q0b = (bf16*)alloc((size_t)16 * SEQ * HD * 2);
  bf16* q1b = (bf16*)alloc((size_t)16 * SEQ * HD * 2);
  bf16* k0b = (bf16*)alloc((size_t)16 * SEQ * HD * 2);
  bf16* k1b = (bf16*)alloc((size_t)16 * SEQ * HD * 2);
  bf16* vt0b = (bf16*)alloc((size_t)16 * HD * SEQ * 2);
  bf16* vt1b = (bf16*)alloc((size_t)16 * HD * SEQ * 2);
  // all-layer weight splits / quants (live across the whole loop)
  bf16* qw0a = (bf16*)alloc((size_t)NLAYER * 3 * DIMD * DIMD * 2);
  bf16* qw1a = (bf16*)alloc((size_t)NLAYER * 3 * DIMD * DIMD * 2);
  bf16* ow0a = (bf16*)alloc((size_t)NLAYER * DIMD * DIMD * 2);
  bf16* ow1a = (bf16*)alloc((size_t)NLAYER * DIMD * DIMD * 2);
  bf16* we1qa = (bf16*)alloc((size_t)NLAYER * EXPERTS * FF * DIMD * 2);
  float* s1a = (float*)alloc((size_t)NLAYER * EXPERTS * FF * 4);
  bf16* we2qa = (bf16*)alloc((size_t)NLAYER * EXPERTS * DIMD * FF * 2);
  float* s2a = (float*)alloc((size_t)NLAYER * EXPERTS * DIMD * 4);

  // ---- union region (time-multiplexed; lifetimes disjoint) ----
  size_t Ustart = off;
  // layout B: per-layer expert activations (gathered, 2048 rows/expert)
  bf16* h0g = (bf16*)alloc((size_t)EXPERTS * 2048 * FF * 2);
  bf16* h1g = (bf16*)alloc((size_t)EXPERTS * 2048 * FF * 2);
  float* yg = (float*)alloc((size_t)EXPERTS * 2048 * DIMD * 4);
  size_t endB = off;
  // layout C: head weights (overlays; dead by head time)
  size_t endC = Ustart + (size_t)HROWS * DIMD * 2;
  bf16* hw0 = (bf16*)(base + Ustart);
  off = endB > endC ? endB : endC;
  if (ws_size < off) return;

  k_embed<<<(NTOK * DIMD + 255) / 256, 256, 0, stream>>>(ids, embed, xAf, xA0,
                                                         xA1);
  // all-layer weight prep (hoisted out of the layer loop)
  k_prepw<<<dim3(512, NLAYER), 256, 0, stream>>>(qkv_w, out_w, qw0a, qw1a,
                                                 ow0a, ow1a);
  k_bitw2<<<dim3(EXPERTS * FF + EXPERTS * DIMD, NLAYER), 256, 0, stream>>>(
      w1, w2, we1qa, s1a, we2qa, s2a);

  for (int l = 0; l < NLAYER; ++l) {
    bf16* qw0 = qw0a + (long)l * 3 * DIMD * DIMD;
    bf16* qw1 = qw1a + (long)l * 3 * DIMD * DIMD;
    bf16* ow0 = ow0a + (long)l * DIMD * DIMD;
    bf16* ow1 = ow1a + (long)l * DIMD * DIMD;
    bf16* we1q = we1qa + (long)l * EXPERTS * FF * DIMD;
    bf16* we2q = we2qa + (long)l * EXPERTS * DIMD * FF;
    float* s1 = s1a + (long)l * EXPERTS * FF;
    float* s2 = s2a + (long)l * EXPERTS * DIMD;
    // fused qkv: x @ qkv_w^T -> q/k 2-splits + v^T 2-splits (mode 5)
    k_mfma_gemm<<<dim3(NTOK / 128, (3 * DIMD) / 128, 1), 256, 0, stream>>>(
        xA0, xA1, qw0, qw1, nullptr, q0b, q1b, k0b, k1b, vt0b, vt1b,
        NTOK, 3 * DIMD, DIMD, 0, 0, 0, 0,
        nullptr, 0, nullptr, 0, nullptr, 0, 5, nullptr, nullptr, 2);
    // fused single-pass flash attention (QBLK=32) -> token-layout 2-split O
    k_fattn<<<dim3(SEQ / 32, 16), 128, 0, stream>>>(q0b, q1b, k0b, k1b,
                                                    vt0b, vt1b, at0, at1);
    // xB = attn_o @ out_w^T + xA  (mode 5; f32 + 2-split out)
    k_mfma_gemm<<<dim3(NTOK / 128, DIMD / 128, 1), 256, 0, stream>>>(
        at0, at1, ow0, ow1, xBf, xB0, xB1, nullptr, nullptr, nullptr,
        nullptr, NTOK, DIMD, DIMD, 0, 0, 0, 0,
        nullptr, 0, nullptr, 0, xAf, 0, 5, nullptr, nullptr, 0);
    k_router<<<NTOK, 64, 0, stream>>>(xBf, router_w + (long)l * EXPERTS * DIMD,
                                      router_b + l * EXPERTS, top2, v2);
    k_expcnt<<<EXPERTS, 256, 0, stream>>>(top2, perm, tokpos, cntb,
                                          xB0 + ND, xB1 + ND);
    // h[e] = gelu((gather(xB) @ q1[e]^T)*s1 + b1)  (mode 3, sparse)
    k_mfma_gemm<<<dim3(NTOK / 128, FF / 128, EXPERTS), 256, 0, stream>>>(
        xB0, xB1, we1q, nullptr, nullptr, h0g, h1g, nullptr, nullptr, nullptr,
        nullptr, NTOK, FF, DIMD, 0, (long)FF * DIMD, 0, (long)2048 * FF,
        s1, FF, b1 + (long)l * EXPERTS * FF, FF, nullptr, 1, 3, cntb, perm, 0);
    // y[e] = (h[e] @ q2[e]^T)*s2 + b2  (mode 3, sparse, f32 out)
    k_mfma_gemm<<<dim3(NTOK / 128, DIMD / 128, EXPERTS), 256, 0, stream>>>(
        h0g, h1g, we2q, nullptr, yg, nullptr, nullptr, nullptr, nullptr,
        nullptr, nullptr, NTOK, DIMD, FF, (long)2048 * FF, (long)DIMD * FF,
        (long)2048 * DIMD, 0, s2, DIMD, b2 + (long)l * EXPERTS * DIMD, DIMD,
        nullptr, 0, 3, cntb, nullptr, 0);
    k_lncomb<<<NTOK, 128, 0, stream>>>(yg, tokpos, v2, xBf, ln_g + l * DIMD,
                                       ln_b + l * DIMD, xAf, xA0, xA1);
  }
  // head: logits = x @ head_w^T  (256² counted-vmcnt pipeline)
  long nh8 = (long)HROWS * DIMD / 8;
  k_headconv<<<(int)((nh8 + 255) / 256), 256, 0, stream>>>(head_w, hw0);
  k_hgemm<<<dim3(NTOK / 256, HROWS / 256, 1), 512, 0, stream>>>(
      xA0, hw0, out, NTOK, VOCABN, DIMD);
}

// Round 20
// 1988.375 us; speedup vs baseline: 1.0439x; 1.0439x over previous
//
#include <hip/hip_runtime.h>
#include <math.h>
#include <stdint.h>

#define NLAYER 6
#define DIMD 512
#define HEADS 8
#define HD 64
#define EXPERTS 8
#define SEQ 1024
#define NTOK 2048
#define FF 1024
#define VOCABN 50257
#define HROWS 50432  // 197*256 zero-padded head rows

typedef __bf16 bf16;
typedef __bf16 bf16x8 __attribute__((ext_vector_type(8)));
typedef __bf16 bf16x4 __attribute__((ext_vector_type(4)));
typedef float f32x4 __attribute__((ext_vector_type(4)));

__device__ __forceinline__ void gl_lds16(const void* g, void* l) {
  __builtin_amdgcn_global_load_lds(
      (const __attribute__((address_space(1))) void*)(uintptr_t)g,
      (__attribute__((address_space(3))) void*)(uintptr_t)l, 16, 0, 0);
}

// LDS element offset for (row, 16B-chunk), BK=32 tiles: XOR swizzle (2-way = free)
#define LDSW(row, kg) (((row) * 32) + ((((kg) ^ (((row) >> 1) & 3))) << 3))

// ====== multi-pass split-bf16 MFMA GEMM, counted-vmcnt pipeline ======
// 128x128 tile, BK=32, double-buffered LDS; steady-state s_waitcnt vmcnt(4)
// keeps one 4-load stage in flight across barriers (T3/T4).
// modes: 0:1p  3:2p(A2,Bexact)  5:3p(A2xB2)
// outmode: 0 normal; 2 qkv-split out: q->(Cb0,Cb1) k->(Cb2,E0) vt->(E1,E2)
__global__ __launch_bounds__(256) void k_mfma_gemm(
    const bf16* __restrict__ A0, const bf16* __restrict__ A1,
    const bf16* __restrict__ B0, const bf16* __restrict__ B1,
    float* __restrict__ Cf, bf16* __restrict__ Cb0, bf16* __restrict__ Cb1,
    bf16* __restrict__ Cb2, bf16* __restrict__ E0, bf16* __restrict__ E1,
    bf16* __restrict__ E2, int M, int N, int K,
    long sA, long sB, long sCf, long sCb,
    const float* __restrict__ colScale, int csStride,
    const float* __restrict__ bias, int biasStride,
    const float* __restrict__ residual, int act, int mode,
    const int* __restrict__ mLimit, const int* __restrict__ aperm,
    int outmode) {
  __shared__ __align__(16) bf16 As[2][128 * 32];
  __shared__ __align__(16) bf16 Bs[2][128 * 32];
  int tid = threadIdx.x;
  int z = blockIdx.z;
  // bijective XCD-aware swizzle (m204)
  int nwg = gridDim.x * gridDim.y;
  int flat = blockIdx.y * gridDim.x + blockIdx.x;
  int qq = nwg >> 3, rr = nwg & 7;
  int xcd = flat & 7, ii = flat >> 3;
  int swz = (xcd < rr ? xcd * (qq + 1) : rr * (qq + 1) + (xcd - rr) * qq) + ii;
  int m0 = (swz % gridDim.x) * 128, n0 = (swz / gridDim.x) * 128;
  if (mLimit && m0 >= mLimit[z]) return;
  int w = tid >> 6, lane = tid & 63;
  int wm = (w >> 1) * 64, wn = (w & 1) * 64;
  int r15 = lane & 15, kg = lane >> 4;

  int pa[3] = {0, 0, 0}, pb[3] = {0, 0, 0};
  int np = 1;
  if (mode == 3) {
    np = 2; pa[1] = 1;
  } else if (mode == 5) {
    np = 3;
    pa[1] = 0; pb[1] = 1; pa[2] = 1; pb[2] = 0;
  }

  f32x4 acc[4][4] = {};
  int srow = tid >> 2;
  // global source chunk pre-swizzled so linear LDS dest == swizzled layout
  int scol = (((tid & 3) ^ ((tid >> 3) & 3))) << 3;
  long arow0, arow1;
  if (aperm) {
    arow0 = aperm[z * 2048 + m0 + srow];
    arow1 = aperm[z * 2048 + m0 + 64 + srow];
  } else {
    arow0 = m0 + srow;
    arow1 = m0 + 64 + srow;
  }
  const bf16* PA[2] = {A0, A1};
  const bf16* PB[2] = {B0, B1};

  // monotone staging state (stage() called exactly nIter times, in order)
  const int kIters = K / 32;
  const int nIter = np * kIters;
  int sp = 0, staged = 0;
  const bf16 *sa0, *sa1, *sb0, *sb1;
  auto resetPassPtrs = [&](int p) {
    const bf16* Az = PA[pa[p]] + (long)z * sA;
    const bf16* Bz = PB[pb[p]] + (long)z * sB;
    sa0 = Az + arow0 * K + scol;
    sa1 = Az + arow1 * K + scol;
    sb0 = Bz + (long)(n0 + srow) * K + scol;
    sb1 = Bz + (long)(n0 + 64 + srow) * K + scol;
  };
  resetPassPtrs(0);
  auto stage = [&](int buf) {
    gl_lds16(sa0, &As[buf][tid * 8]);
    gl_lds16(sa1, &As[buf][2048 + tid * 8]);
    gl_lds16(sb0, &Bs[buf][tid * 8]);
    gl_lds16(sb1, &Bs[buf][2048 + tid * 8]);
    sa0 += 32; sa1 += 32; sb0 += 32; sb1 += 32;
    if (++staged == kIters) {
      staged = 0;
      if (++sp < np) resetPassPtrs(sp);
    }
  };
  auto compute = [&](int buf) {
    bf16x8 af[4], bfr[4];
#pragma unroll
    for (int mi = 0; mi < 4; ++mi) {
      int rowA = wm + mi * 16 + r15;
      af[mi] = *(const bf16x8*)&As[buf][LDSW(rowA, kg)];
    }
#pragma unroll
    for (int ni = 0; ni < 4; ++ni) {
      int rowB = wn + ni * 16 + r15;
      bfr[ni] = *(const bf16x8*)&Bs[buf][LDSW(rowB, kg)];
    }
#pragma unroll
    for (int mi = 0; mi < 4; ++mi)
#pragma unroll
      for (int ni = 0; ni < 4; ++ni)
        acc[mi][ni] = __builtin_amdgcn_mfma_f32_16x16x32_bf16(
            af[mi], bfr[ni], acc[mi][ni], 0, 0, 0);
  };

  stage(0);
  stage(1);
#pragma unroll 1
  for (int it = 0; it < nIter - 2; ++it) {
    asm volatile("s_waitcnt vmcnt(4)" ::: "memory");  // stage it landed
    __builtin_amdgcn_s_barrier();                     // publish cross-wave
    __builtin_amdgcn_sched_barrier(0);
    compute(it & 1);
    __builtin_amdgcn_s_barrier();  // readers done with buf (it&1)
    stage(it & 1);                 // restage freed buffer; stays in flight
  }
  asm volatile("s_waitcnt vmcnt(4)" ::: "memory");
  __builtin_amdgcn_s_barrier();
  __builtin_amdgcn_sched_barrier(0);
  compute(nIter & 1);
  asm volatile("s_waitcnt vmcnt(0)" ::: "memory");
  __builtin_amdgcn_s_barrier();
  __builtin_amdgcn_sched_barrier(0);
  compute((nIter - 1) & 1);

  // C/D layout: col=lane&15, row=(lane>>4)*4+reg  [m89]
#pragma unroll
  for (int mi = 0; mi < 4; ++mi) {
    int rbase = m0 + wm + mi * 16 + kg * 4;
#pragma unroll
    for (int ni = 0; ni < 4; ++ni) {
      int col = n0 + wn + ni * 16 + r15;
      if (col >= N) continue;
      float scl = colScale ? colScale[z * csStride + col] : 1.f;
      float bv = bias ? bias[z * biasStride + col] : 0.f;
#pragma unroll
      for (int reg = 0; reg < 4; ++reg) {
        int row = rbase + reg;
        float v = acc[mi][ni][reg] * scl + bv;
        if (act) v = 0.5f * v * (1.f + erff(v * 0.70710678118654752f));
        if (residual) v += residual[(long)row * N + col];
        if (outmode == 2) {
          int b = row >> 10, qt = row & 1023;
          if (n0 < 512) {  // Q, pre-scaled by 0.125 (exact)
            float qv = v * 0.125f;
            int h = col >> 6, d = col & 63;
            long dst = ((long)(b * 8 + h)) * ((long)SEQ * HD) +
                       (long)qt * HD + d;
            bf16 h0 = (bf16)qv;
            Cb0[dst] = h0;
            Cb1[dst] = (bf16)(qv - (float)h0);
          } else if (n0 < 1024) {  // K
            int c2 = col - 512;
            int h = c2 >> 6, d = c2 & 63;
            long dst = ((long)(b * 8 + h)) * ((long)SEQ * HD) +
                       (long)qt * HD + d;
            bf16 h0 = (bf16)v;
            Cb2[dst] = h0;
            E0[dst] = (bf16)(v - (float)h0);
          } else {  // V^T: [bh][d=64][k]
            int c2 = col - 1024;
            int h = c2 >> 6, d = c2 & 63;
            long dst = ((long)(b * 8 + h)) * ((long)HD * SEQ) +
                       (long)d * SEQ + qt;
            bf16 h0 = (bf16)v;
            E1[dst] = h0;
            E2[dst] = (bf16)(v - (float)h0);
          }
          continue;
        }
        if (Cf) Cf[z * sCf + (long)row * N + col] = v;
        if (Cb0) {
          long cib = z * sCb + (long)row * N + col;
          bf16 h0 = (bf16)v;
          Cb0[cib] = h0;
          if (Cb1) {
            float r = v - (float)h0;
            Cb1[cib] = (bf16)r;
          }
        }
      }
    }
  }
}

// ====== fused SINGLE-PASS flash attention, KVBLK=64 (48 KB LDS, 3 blk/CU) ======
// block = (64 q-rows, bh); 4 waves, wave = 16 q-rows. Per 64-wide K-tile:
// S = QK^T (3 split-combos), online (m,l) update, rescale O, unnormalized
// exp(S-m) -> 2-split P in wave-private swizzled LDS, PV accumulate.
__global__ __launch_bounds__(256) void k_fattn(
    const bf16* __restrict__ q0b, const bf16* __restrict__ q1b,
    const bf16* __restrict__ k0b, const bf16* __restrict__ k1b,
    const bf16* __restrict__ vt0, const bf16* __restrict__ vt1,
    bf16* __restrict__ at0, bf16* __restrict__ at1) {
  __shared__ __align__(16) bf16 Ks[2][64 * 64];
  __shared__ __align__(16) bf16 Vs[2][64 * 64];
  __shared__ __align__(16) bf16 Ps[2][64 * 64];
  int tid = threadIdx.x;
  int bh = blockIdx.y;
  int q0 = blockIdx.x * 64;
  int w = tid >> 6, lane = tid & 63;
  int r15 = lane & 15, kg = lane >> 4;
  const long bhQK = (long)bh * SEQ * HD;
  const long bhV = (long)bh * HD * SEQ;

  // Q fragments in registers (Q already scaled by 0.125 at qkv epilogue)
  bf16x8 qa0[2], qa1[2];
  {
    long qoff = bhQK + (long)(q0 + w * 16 + r15) * HD;
#pragma unroll
    for (int ks = 0; ks < 2; ++ks) {
      qa0[ks] = *(const bf16x8*)&q0b[qoff + ks * 32 + kg * 8];
      qa1[ks] = *(const bf16x8*)&q1b[qoff + ks * 32 + kg * 8];
    }
  }

  // stage K-tile (64x64, 2 splits) with pre-swizzled source (rule #21)
  auto stageK = [&](int kt) {
#pragma unroll
    for (int i = 0; i < 2; ++i) {
      int L = tid + i * 256;
      int row = L >> 3, pc = L & 7;
      int gc = pc ^ (row & 7);
      long gsrc = bhQK + (long)(kt * 64 + row) * HD + gc * 8;
      gl_lds16(k0b + gsrc, &Ks[0][L * 8]);
      gl_lds16(k1b + gsrc, &Ks[1][L * 8]);
    }
  };
  // stage V-tile (V^T 64 d-rows x 64 k-cols, 2 splits)
  auto stageV = [&](int kt) {
#pragma unroll
    for (int i = 0; i < 2; ++i) {
      int L = tid + i * 256;
      int row = L >> 3, pc = L & 7;
      int gc = pc ^ (row & 7);
      long gsrc = bhV + (long)row * SEQ + kt * 64 + gc * 8;
      gl_lds16(vt0 + gsrc, &Vs[0][L * 8]);
      gl_lds16(vt1 + gsrc, &Vs[1][L * 8]);
    }
  };
  // sf[kc]: k-cols kc*16+r15 (kc 0..3), q-rows kg*4+reg (C/D layout m89)
  auto computeS = [&](f32x4* sf) {
    __builtin_amdgcn_s_setprio(1);
#pragma unroll
    for (int kc = 0; kc < 4; ++kc) {
      f32x4 a = {};
      int rowB = kc * 16 + r15;
#pragma unroll
      for (int ks = 0; ks < 2; ++ks) {
        int pc = (ks * 4 + kg) ^ (rowB & 7);
        bf16x8 b0 = *(const bf16x8*)&Ks[0][rowB * 64 + pc * 8];
        bf16x8 b1 = *(const bf16x8*)&Ks[1][rowB * 64 + pc * 8];
        a = __builtin_amdgcn_mfma_f32_16x16x32_bf16(qa0[ks], b0, a, 0, 0, 0);
        a = __builtin_amdgcn_mfma_f32_16x16x32_bf16(qa0[ks], b1, a, 0, 0, 0);
        a = __builtin_amdgcn_mfma_f32_16x16x32_bf16(qa1[ks], b0, a, 0, 0, 0);
      }
      sf[kc] = a;
    }
    __builtin_amdgcn_s_setprio(0);
  };

  float m[4], l[4];
#pragma unroll
  for (int r = 0; r < 4; ++r) { m[r] = -1e30f; l[r] = 0.f; }
  f32x4 oacc[4] = {};

  for (int kt = 0; kt < SEQ / 64; ++kt) {
    stageK(kt);
    stageV(kt);
    __syncthreads();  // drains vmcnt: K,V ready
    f32x4 sf[4];
    computeS(sf);
    // online stats + rescale O; P = exp(S - m_new) (unnormalized)
#pragma unroll
    for (int r = 0; r < 4; ++r) {
      float tm = sf[0][r];
#pragma unroll
      for (int kc = 1; kc < 4; ++kc) tm = fmaxf(tm, sf[kc][r]);
      tm = fmaxf(tm, __shfl_xor(tm, 1));
      tm = fmaxf(tm, __shfl_xor(tm, 2));
      tm = fmaxf(tm, __shfl_xor(tm, 4));
      tm = fmaxf(tm, __shfl_xor(tm, 8));
      float mn = fmaxf(m[r], tm);
      float corr = __expf(m[r] - mn);
      float s = 0.f;
#pragma unroll
      for (int kc = 0; kc < 4; ++kc) {
        float p = __expf(sf[kc][r] - mn);
        sf[kc][r] = p;
        s += p;
      }
      s += __shfl_xor(s, 1);
      s += __shfl_xor(s, 2);
      s += __shfl_xor(s, 4);
      s += __shfl_xor(s, 8);
      l[r] = l[r] * corr + s;
      m[r] = mn;
#pragma unroll
      for (int dg = 0; dg < 4; ++dg) oacc[dg][r] *= corr;
    }
    // P -> 2-split bf16 into wave-private swizzled Ps rows
#pragma unroll
    for (int kc = 0; kc < 4; ++kc) {
#pragma unroll
      for (int r = 0; r < 4; ++r) {
        float p = sf[kc][r];
        bf16 h0 = (bf16)p;
        bf16 h1 = (bf16)(p - (float)h0);
        int qrow = w * 16 + kg * 4 + r;
        int kcol = kc * 16 + r15;
        int pc = (kcol >> 3) ^ (qrow & 7);
        int addr = qrow * 64 + pc * 8 + (kcol & 7);
        Ps[0][addr] = h0;
        Ps[1][addr] = h1;
      }
    }
    // PV (Ps rows are wave-private: same-wave lgkmcnt ordering suffices)
    bf16x8 pa0[2], pa1[2];
    int rowP = w * 16 + r15;
#pragma unroll
    for (int ks = 0; ks < 2; ++ks) {
      int pc = (ks * 4 + kg) ^ (rowP & 7);
      pa0[ks] = *(const bf16x8*)&Ps[0][rowP * 64 + pc * 8];
      pa1[ks] = *(const bf16x8*)&Ps[1][rowP * 64 + pc * 8];
    }
    __builtin_amdgcn_s_setprio(1);
#pragma unroll
    for (int dg = 0; dg < 4; ++dg) {
      int rowV = dg * 16 + r15;
#pragma unroll
      for (int ks = 0; ks < 2; ++ks) {
        int pc = (ks * 4 + kg) ^ (rowV & 7);
        bf16x8 v0 = *(const bf16x8*)&Vs[0][rowV * 64 + pc * 8];
        bf16x8 v1 = *(const bf16x8*)&Vs[1][rowV * 64 + pc * 8];
        oacc[dg] = __builtin_amdgcn_mfma_f32_16x16x32_bf16(pa0[ks], v0,
                                                           oacc[dg], 0, 0, 0);
        oacc[dg] = __builtin_amdgcn_mfma_f32_16x16x32_bf16(pa0[ks], v1,
                                                           oacc[dg], 0, 0, 0);
        oacc[dg] = __builtin_amdgcn_mfma_f32_16x16x32_bf16(pa1[ks], v0,
                                                           oacc[dg], 0, 0, 0);
      }
    }
    __builtin_amdgcn_s_setprio(0);
    __syncthreads();  // all waves done reading Ks/Vs before restage
  }

  float invl[4];
#pragma unroll
  for (int r = 0; r < 4; ++r) invl[r] = 1.f / l[r];

  // epilogue: token-layout 2-split O
  int b = bh >> 3, h = bh & 7;
#pragma unroll
  for (int dg = 0; dg < 4; ++dg) {
#pragma unroll
    for (int r = 0; r < 4; ++r) {
      int qrow = q0 + w * 16 + kg * 4 + r;
      int d = dg * 16 + r15;
      long dst = ((long)(b * SEQ + qrow)) * DIMD + h * HD + d;
      float v = oacc[dg][r] * invl[r];
      bf16 h0 = (bf16)v;
      at0[dst] = h0;
      at1[dst] = (bf16)(v - (float)h0);
    }
  }
}

// ====== head GEMM: 256x256 tile, BK=64, 8 waves, counted-vmcnt pipeline ======
__global__ __launch_bounds__(512, 2) void k_hgemm(const bf16* __restrict__ A,
                                                  const bf16* __restrict__ Bt,
                                                  float* __restrict__ C,
                                                  int M, int N, int K) {
  __shared__ __align__(16) bf16 As[2][256 * 64];
  __shared__ __align__(16) bf16 Bs[2][256 * 64];
  int tid = threadIdx.x;
  int nwg = gridDim.x * gridDim.y;
  int flat = blockIdx.y * gridDim.x + blockIdx.x;
  int qq = nwg >> 3, rr = nwg & 7;
  int xcd = flat & 7, ii = flat >> 3;
  int swz = (xcd < rr ? xcd * (qq + 1) : rr * (qq + 1) + (xcd - rr) * qq) + ii;
  int m0 = (swz % gridDim.x) * 256, n0 = (swz / gridDim.x) * 256;
  int w = tid >> 6, lane = tid & 63;
  int wm = (w >> 2) * 128, wn = (w & 3) * 64;  // 2M x 4N waves
  int r15 = lane & 15, kg = lane >> 4;

  auto stage = [&](int buf, int kt) {
#pragma unroll
    for (int j = 0; j < 4; ++j) {
      int L = tid + j * 512;
      int row = L >> 3, pc = L & 7;
      int gc = pc ^ (row & 7);  // pre-swizzled source, linear LDS dest
      gl_lds16(A + (long)(m0 + row) * K + kt * 64 + gc * 8, &As[buf][L * 8]);
      gl_lds16(Bt + (long)(n0 + row) * K + kt * 64 + gc * 8, &Bs[buf][L * 8]);
    }
  };

  f32x4 acc[8][4] = {};
  auto compute = [&](int buf) {
#pragma unroll
    for (int ks = 0; ks < 2; ++ks) {
      bf16x8 af[8], bf_[4];
#pragma unroll
      for (int mi = 0; mi < 8; ++mi) {
        int row = wm + mi * 16 + r15;
        af[mi] = *(const bf16x8*)
            &As[buf][row * 64 + ((((ks * 4 + kg) ^ (row & 7))) << 3)];
      }
#pragma unroll
      for (int ni = 0; ni < 4; ++ni) {
        int row = wn + ni * 16 + r15;
        bf_[ni] = *(const bf16x8*)
            &Bs[buf][row * 64 + ((((ks * 4 + kg) ^ (row & 7))) << 3)];
      }
#pragma unroll
      for (int mi = 0; mi < 8; ++mi)
#pragma unroll
        for (int ni = 0; ni < 4; ++ni)
          acc[mi][ni] = __builtin_amdgcn_mfma_f32_16x16x32_bf16(
              af[mi], bf_[ni], acc[mi][ni], 0, 0, 0);
    }
  };

  stage(0, 0);
  stage(1, 1);
#pragma unroll 1
  for (int t = 0; t < 6; ++t) {
    asm volatile("s_waitcnt vmcnt(8)" ::: "memory");  // tile t landed
    __builtin_amdgcn_s_barrier();                     // publish cross-wave
    __builtin_amdgcn_sched_barrier(0);
    compute(t & 1);
    __builtin_amdgcn_s_barrier();  // all waves done reading buf (t&1)
    stage(t & 1, t + 2);           // restage freed buffer; stays in flight
  }
  asm volatile("s_waitcnt vmcnt(8)" ::: "memory");
  __builtin_amdgcn_s_barrier();
  __builtin_amdgcn_sched_barrier(0);
  compute(0);
  asm volatile("s_waitcnt vmcnt(0)" ::: "memory");
  __builtin_amdgcn_s_barrier();
  __builtin_amdgcn_sched_barrier(0);
  compute(1);

  // epilogue: C/D layout col=lane&15, row=(lane>>4)*4+reg  [m89]
#pragma unroll
  for (int mi = 0; mi < 8; ++mi) {
    int rbase = m0 + wm + mi * 16 + kg * 4;
#pragma unroll
    for (int ni = 0; ni < 4; ++ni) {
      int col = n0 + wn + ni * 16 + r15;
      if (col >= N) continue;
#pragma unroll
      for (int reg = 0; reg < 4; ++reg)
        C[(long)(rbase + reg) * N + col] = acc[mi][ni][reg];
    }
  }
}

// ---------------- helpers ----------------
__global__ __launch_bounds__(256) void k_embed(const int* __restrict__ ids,
                                               const float* __restrict__ E,
                                               float* __restrict__ xf,
                                               bf16* __restrict__ x0,
                                               bf16* __restrict__ x1) {
  int i = blockIdx.x * 256 + threadIdx.x;
  if (i >= NTOK * DIMD) return;
  int n = i >> 9, d = i & 511;
  float v = E[(long)ids[n] * DIMD + d];
  xf[i] = v;
  bf16 b0 = (bf16)v;
  x0[i] = b0;
  x1[i] = (bf16)(v - (float)b0);
}

// ALL-layer weight split: grid (512, NLAYER); qkv_w chunks then out_w chunks
__global__ __launch_bounds__(256) void k_prepw(const float* __restrict__ qkv_w,
                                               const float* __restrict__ out_w,
                                               bf16* __restrict__ qw0a,
                                               bf16* __restrict__ qw1a,
                                               bf16* __restrict__ ow0a,
                                               bf16* __restrict__ ow1a) {
  int l = blockIdx.y;
  const long n8q = (long)3 * DIMD * DIMD / 8;
  long i = (long)blockIdx.x * 256 + threadIdx.x;
  const float* s;
  bf16 *d0, *d1;
  long j;
  if (i < n8q) {
    s = qkv_w + (long)l * 3 * DIMD * DIMD;
    d0 = qw0a + (long)l * 3 * DIMD * DIMD;
    d1 = qw1a + (long)l * 3 * DIMD * DIMD;
    j = i;
  } else {
    s = out_w + (long)l * DIMD * DIMD;
    d0 = ow0a + (long)l * DIMD * DIMD;
    d1 = ow1a + (long)l * DIMD * DIMD;
    j = i - n8q;
  }
  const float4* s4 = (const float4*)s;
  float4 a = s4[2 * j], b = s4[2 * j + 1];
  float vv[8] = {a.x, a.y, a.z, a.w, b.x, b.y, b.z, b.w};
  bf16x8 o0, o1;
#pragma unroll
  for (int k = 0; k < 8; ++k) {
    float v = vv[k];
    bf16 h0 = (bf16)v;
    o0[k] = h0;
    o1[k] = (bf16)(v - (float)h0);
  }
  ((bf16x8*)d0)[j] = o0;
  ((bf16x8*)d1)[j] = o1;
}

__global__ __launch_bounds__(256) void k_headconv(const float* __restrict__ s,
                                                  bf16* __restrict__ d) {
  long i = (long)blockIdx.x * 256 + threadIdx.x;
  long n8 = (long)HROWS * DIMD / 8;
  if (i >= n8) return;
  long row = i / (DIMD / 8);
  bf16x8 o;
  if (row < VOCABN) {
    const float4* s4 = (const float4*)s;
    float4 a = s4[2 * i], b = s4[2 * i + 1];
    o[0] = (bf16)a.x; o[1] = (bf16)a.y; o[2] = (bf16)a.z; o[3] = (bf16)a.w;
    o[4] = (bf16)b.x; o[5] = (bf16)b.y; o[6] = (bf16)b.z; o[7] = (bf16)b.w;
  } else {
    o = (bf16x8)(bf16)0.f;
  }
  ((bf16x8*)d)[i] = o;
}

// router: top-2 expert ids + normalized weights per token
__global__ __launch_bounds__(64) void k_router(const float* __restrict__ x,
                                               const float* __restrict__ rw,
                                               const float* __restrict__ rb,
                                               int* __restrict__ top2,
                                               float* __restrict__ v2) {
  int n = blockIdx.x;
  int t = threadIdx.x;
  int e = t >> 3, part = t & 7;
  __shared__ float red[64];
  const float* xr = x + (long)n * DIMD;
  const float* wr = rw + (long)e * DIMD;
  float d = 0.f;
  int c0 = part * 64;
#pragma unroll
  for (int c = 0; c < 64; c += 4) {
    float4 xv = *(const float4*)(xr + c0 + c);
    float4 wv = *(const float4*)(wr + c0 + c);
    d += xv.x * wv.x + xv.y * wv.y + xv.z * wv.z + xv.w * wv.w;
  }
  red[t] = d;
  __syncthreads();
  if (t < 8) {
    float logit = rb[t];
    for (int pp = 0; pp < 8; ++pp) logit += red[t * 8 + pp];
    red[t] = logit;
  }
  __syncthreads();
  if (t == 0) {
    float p2[8];
    float m = -1e30f;
    for (int i = 0; i < 8; ++i) m = fmaxf(m, red[i]);
    float s = 0.f;
    for (int i = 0; i < 8; ++i) { p2[i] = expf(red[i] - m); s += p2[i]; }
    for (int i = 0; i < 8; ++i) p2[i] /= s;
    int i1 = 0;
    for (int i = 1; i < 8; ++i) if (p2[i] > p2[i1]) i1 = i;
    int i2 = (i1 == 0) ? 1 : 0;
    for (int i = 0; i < 8; ++i) {
      if (i == i1 || i == i2) continue;
      if (p2[i] > p2[i2]) i2 = i;
    }
    float sum = p2[i1] + p2[i2] + 1e-8f;
    top2[2 * n] = i1;
    top2[2 * n + 1] = i2;
    v2[2 * n] = p2[i1] / sum;
    v2[2 * n + 1] = p2[i2] / sum;
  }
}

// per-expert token lists, one-pass 8-elem/thread prefix scan (deterministic)
__global__ __launch_bounds__(256) void k_expcnt(const int* __restrict__ top2,
                                                int* __restrict__ perm,
                                                int* __restrict__ tokpos,
                                                int* __restrict__ cnt,
                                                bf16* __restrict__ zx0,
                                                bf16* __restrict__ zx1) {
  int e = blockIdx.x, t = threadIdx.x;
  if (e == 0) {
    for (int c = t; c < DIMD; c += 256) {
      zx0[c] = (bf16)0.f;
      zx1[c] = (bf16)0.f;
    }
  }
  __shared__ int sc[256];
  int fl[8];
  int f = 0;
#pragma unroll
  for (int j = 0; j < 8; ++j) {
    int n = t * 8 + j;
    int m = (top2[2 * n] == e || top2[2 * n + 1] == e) ? 1 : 0;
    fl[j] = m;
    f += m;
  }
  sc[t] = f;
  __syncthreads();
  for (int o = 1; o < 256; o <<= 1) {
    int v = (t >= o) ? sc[t - o] : 0;
    __syncthreads();
    sc[t] += v;
    __syncthreads();
  }
  int pos = sc[t] - f;  // exclusive prefix
#pragma unroll
  for (int j = 0; j < 8; ++j) {
    if (fl[j]) {
      int n = t * 8 + j;
      perm[e * 2048 + pos] = n;
      int jj = (top2[2 * n] == e) ? 0 : 1;
      tokpos[2 * n + jj] = e * 2048 + pos;
      ++pos;
    }
  }
  int total = sc[255];
  int cpad = (total + 127) & ~127;
  for (int i = total + t; i < cpad; i += 256) perm[e * 2048 + i] = 2048;
  if (t == 0) cnt[e] = total;
}

// ALL-layer BitNet quant: grid (12288, NLAYER); blocks [0,8192)=we1 rows
__global__ __launch_bounds__(256) void k_bitw2(const float* __restrict__ w1,
                                               const float* __restrict__ w2,
                                               bf16* __restrict__ we1qa,
                                               float* __restrict__ s1a,
                                               bf16* __restrict__ we2qa,
                                               float* __restrict__ s2a) {
  int l = blockIdx.y;
  int blk = blockIdx.x;
  int t = threadIdx.x;
  const float* wr;
  bf16* outr;
  float* sOut;
  int cols;
  if (blk < EXPERTS * FF) {
    cols = DIMD;
    wr = w1 + (long)l * EXPERTS * FF * DIMD + (long)blk * cols;
    outr = we1qa + (long)l * EXPERTS * FF * DIMD + (long)blk * cols;
    sOut = s1a + (long)l * EXPERTS * FF + blk;
  } else {
    int row = blk - EXPERTS * FF;
    cols = FF;
    wr = w2 + (long)l * EXPERTS * DIMD * FF + (long)row * cols;
    outr = we2qa + (long)l * EXPERTS * DIMD * FF + (long)row * cols;
    sOut = s2a + (long)l * EXPERTS * DIMD + row;
  }
  float acc = 0.f;
  for (int c = t; c < cols; c += 256) acc += fabsf(wr[c]);
  __shared__ float red[256];
  red[t] = acc;
  __syncthreads();
  for (int off = 128; off; off >>= 1) {
    if (t < off) red[t] += red[t + off];
    __syncthreads();
  }
  float scale = fmaxf(red[0] / (float)cols, 1e-5f);
  if (t == 0) *sOut = scale;
  for (int c = t; c < cols; c += 256) {
    float qv = rintf(wr[c] / scale);  // RNE, matches jnp.round
    qv = fmaxf(-1.f, fminf(1.f, qv));
    outr[c] = (bf16)qv;
  }
}

// combine top-2 experts (gathered f32 y), add residual, LN -> f32 + 2-split
__global__ __launch_bounds__(128) void k_lncomb(
    const float* __restrict__ yg, const int* __restrict__ tokpos,
    const float* __restrict__ v2, const float* __restrict__ xBf,
    const float* __restrict__ g, const float* __restrict__ b,
    float* __restrict__ xof, bf16* __restrict__ x0, bf16* __restrict__ x1) {
  int n = blockIdx.x;
  int t = threadIdx.x;
  __shared__ float red[128];
  long tp0 = tokpos[2 * n], tp1 = tokpos[2 * n + 1];
  float w0 = v2[2 * n], w1 = v2[2 * n + 1];
  const float* y0 = yg + tp0 * DIMD;
  const float* y1 = yg + tp1 * DIMD;
  float u[4];
  float s = 0.f;
#pragma unroll
  for (int i = 0; i < 4; ++i) {
    int d = t + i * 128;
    float v = xBf[(long)n * DIMD + d] + w0 * y0[d] + w1 * y1[d];
    u[i] = v;
    s += v;
  }
  red[t] = s;
  __syncthreads();
  for (int off = 64; off; off >>= 1) {
    if (t < off) red[t] += red[t + off];
    __syncthreads();
  }
  float mu = red[0] / (float)DIMD;
  __syncthreads();
  float var = 0.f;
#pragma unroll
  for (int i = 0; i < 4; ++i) {
    float d = u[i] - mu;
    var += d * d;
  }
  red[t] = var;
  __syncthreads();
  for (int off = 64; off; off >>= 1) {
    if (t < off) red[t] += red[t + off];
    __syncthreads();
  }
  float inv = 1.f / sqrtf(red[0] / (float)DIMD + 1e-5f);
#pragma unroll
  for (int i = 0; i < 4; ++i) {
    int c = t + i * 128;
    float v = (u[i] - mu) * inv * g[c] + b[c];
    long oi = (long)n * DIMD + c;
    xof[oi] = v;
    bf16 b0 = (bf16)v;
    x0[oi] = b0;
    x1[oi] = (bf16)(v - (float)b0);
  }
}

extern "C" void kernel_launch(void* const* d_in, const int* in_sizes, int n_in,
                              void* d_out, int out_size, void* d_ws, size_t ws_size,
                              hipStream_t stream) {
  const int* ids = (const int*)d_in[0];
  const float* embed = (const float*)d_in[1];
  const float* qkv_w = (const float*)d_in[2];
  const float* out_w = (const float*)d_in[3];
  const float* router_w = (const float*)d_in[4];
  const float* router_b = (const float*)d_in[5];
  const float* w1 = (const float*)d_in[6];
  const float* b1 = (const float*)d_in[7];
  const float* w2 = (const float*)d_in[8];
  const float* b2 = (const float*)d_in[9];
  const float* ln_g = (const float*)d_in[10];
  const float* ln_b = (const float*)d_in[11];
  const float* head_w = (const float*)d_in[12];
  float* out = (float*)d_out;

  char* base = (char*)d_ws;
  size_t off = 0;
  auto alloc = [&](size_t bytes) -> void* {
    void* p = base + off;
    off += (bytes + 255) & ~(size_t)255;
    return p;
  };
  const size_t ND = (size_t)NTOK * DIMD;
  float* xAf = (float*)alloc(ND * 4);
  float* xBf = (float*)alloc(ND * 4);
  int* top2 = (int*)alloc((size_t)NTOK * 2 * 4);
  float* v2 = (float*)alloc((size_t)NTOK * 2 * 4);
  int* perm = (int*)alloc((size_t)EXPERTS * 2048 * 4);
  int* tokpos = (int*)alloc((size_t)NTOK * 2 * 4);
  int* cntb = (int*)alloc(64);
  bf16* xA0 = (bf16*)alloc(ND * 2);
  bf16* xA1 = (bf16*)alloc(ND * 2);
  bf16* xB0 = (bf16*)alloc((ND + DIMD) * 2);  // +1 zero row (idx 2048)
  bf16* xB1 = (bf16*)alloc((ND + DIMD) * 2);
  bf16* at0 = (bf16*)alloc(ND * 2);
  bf16* at1 = (bf16*)alloc(ND * 2);
  bf16* q0b = (bf16*)alloc((size_t)16 * SEQ * HD * 2);
  bf16* q1b = (bf16*)alloc((size_t)16 * SEQ * HD * 2);
  bf16* k0b = (bf16*)alloc((size_t)16 * SEQ * HD * 2);
  bf16* k1b = (bf16*)alloc((size_t)16 * SEQ * HD * 2);
  bf16* vt0b = (bf16*)alloc((size_t)16 * HD * SEQ * 2);
  bf16* vt1b = (bf16*)alloc((size_t)16 * HD * SEQ * 2);
  // all-layer weight splits / quants (live across the whole loop)
  bf16* qw0a = (bf16*)alloc((size_t)NLAYER * 3 * DIMD * DIMD * 2);
  bf16* qw1a = (bf16*)alloc((size_t)NLAYER * 3 * DIMD * DIMD * 2);
  bf16* ow0a = (bf16*)alloc((size_t)NLAYER * DIMD * DIMD * 2);
  bf16* ow1a = (bf16*)alloc((size_t)NLAYER * DIMD * DIMD * 2);
  bf16* we1qa = (bf16*)alloc((size_t)NLAYER * EXPERTS * FF * DIMD * 2);
  float* s1a = (float*)alloc((size_t)NLAYER * EXPERTS * FF * 4);
  bf16* we2qa = (bf16*)alloc((size_t)NLAYER * EXPERTS * DIMD * FF * 2);
  float* s2a = (float*)alloc((size_t)NLAYER * EXPERTS * DIMD * 4);

  // ---- union region (time-multiplexed; lifetimes disjoint) ----
  size_t Ustart = off;
  // layout B: per-layer expert activations (gathered, 2048 rows/expert)
  bf16* h0g = (bf16*)alloc((size_t)EXPERTS * 2048 * FF * 2);
  bf16* h1g = (bf16*)alloc((size_t)EXPERTS * 2048 * FF * 2);
  float* yg = (float*)alloc((size_t)EXPERTS * 2048 * DIMD * 4);
  size_t endB = off;
  // layout C: head weights (overlays; dead by head time)
  size_t endC = Ustart + (size_t)HROWS * DIMD * 2;
  bf16* hw0 = (bf16*)(base + Ustart);
  off = endB > endC ? endB : endC;
  if (ws_size < off) return;

  k_embed<<<(NTOK * DIMD + 255) / 256, 256, 0, stream>>>(ids, embed, xAf, xA0,
                                                         xA1);
  // all-layer weight prep (hoisted out of the layer loop)
  k_prepw<<<dim3(512, NLAYER), 256, 0, stream>>>(qkv_w, out_w, qw0a, qw1a,
                                                 ow0a, ow1a);
  k_bitw2<<<dim3(EXPERTS * FF + EXPERTS * DIMD, NLAYER), 256, 0, stream>>>(
      w1, w2, we1qa, s1a, we2qa, s2a);

  for (int l = 0; l < NLAYER; ++l) {
    bf16* qw0 = qw0a + (long)l * 3 * DIMD * DIMD;
    bf16* qw1 = qw1a + (long)l * 3 * DIMD * DIMD;
    bf16* ow0 = ow0a + (long)l * DIMD * DIMD;
    bf16* ow1 = ow1a + (long)l * DIMD * DIMD;
    bf16* we1q = we1qa + (long)l * EXPERTS * FF * DIMD;
    bf16* we2q = we2qa + (long)l * EXPERTS * DIMD * FF;
    float* s1 = s1a + (long)l * EXPERTS * FF;
    float* s2 = s2a + (long)l * EXPERTS * DIMD;
    // fused qkv: x @ qkv_w^T -> q/k 2-splits + v^T 2-splits (mode 5)
    k_mfma_gemm<<<dim3(NTOK / 128, (3 * DIMD) / 128, 1), 256, 0, stream>>>(
        xA0, xA1, qw0, qw1, nullptr, q0b, q1b, k0b, k1b, vt0b, vt1b,
        NTOK, 3 * DIMD, DIMD, 0, 0, 0, 0,
        nullptr, 0, nullptr, 0, nullptr, 0, 5, nullptr, nullptr, 2);
    // fused single-pass flash attention (KVBLK=64) -> token-layout 2-split O
    k_fattn<<<dim3(SEQ / 64, 16), 256, 0, stream>>>(q0b, q1b, k0b, k1b,
                                                    vt0b, vt1b, at0, at1);
    // xB = attn_o @ out_w^T + xA  (mode 5; f32 + 2-split out)
    k_mfma_gemm<<<dim3(NTOK / 128, DIMD / 128, 1), 256, 0, stream>>>(
        at0, at1, ow0, ow1, xBf, xB0, xB1, nullptr, nullptr, nullptr,
        nullptr, NTOK, DIMD, DIMD, 0, 0, 0, 0,
        nullptr, 0, nullptr, 0, xAf, 0, 5, nullptr, nullptr, 0);
    k_router<<<NTOK, 64, 0, stream>>>(xBf, router_w + (long)l * EXPERTS * DIMD,
                                      router_b + l * EXPERTS, top2, v2);
    k_expcnt<<<EXPERTS, 256, 0, stream>>>(top2, perm, tokpos, cntb,
                                          xB0 + ND, xB1 + ND);
    // h[e] = gelu((gather(xB) @ q1[e]^T)*s1 + b1)  (mode 3, sparse)
    k_mfma_gemm<<<dim3(NTOK / 128, FF / 128, EXPERTS), 256, 0, stream>>>(
        xB0, xB1, we1q, nullptr, nullptr, h0g, h1g, nullptr, nullptr, nullptr,
        nullptr, NTOK, FF, DIMD, 0, (long)FF * DIMD, 0, (long)2048 * FF,
        s1, FF, b1 + (long)l * EXPERTS * FF, FF, nullptr, 1, 3, cntb, perm, 0);
    // y[e] = (h[e] @ q2[e]^T)*s2 + b2  (mode 3, sparse, f32 out)
    k_mfma_gemm<<<dim3(NTOK / 128, DIMD / 128, EXPERTS), 256, 0, stream>>>(
        h0g, h1g, we2q, nullptr, yg, nullptr, nullptr, nullptr, nullptr,
        nullptr, nullptr, NTOK, DIMD, FF, (long)2048 * FF, (long)DIMD * FF,
        (long)2048 * DIMD, 0, s2, DIMD, b2 + (long)l * EXPERTS * DIMD, DIMD,
        nullptr, 0, 3, cntb, nullptr, 0);
    k_lncomb<<<NTOK, 128, 0, stream>>>(yg, tokpos, v2, xBf, ln_g + l * DIMD,
                                       ln_b + l * DIMD, xAf, xA0, xA1);
  }
  // head: logits = x @ head_w^T  (256² counted-vmcnt pipeline)
  long nh8 = (long)HROWS * DIMD / 8;
  k_headconv<<<(int)((nh8 + 255) / 256), 256, 0, stream>>>(head_w, hw0);
  k_hgemm<<<dim3(NTOK / 256, HROWS / 256, 1), 512, 0, stream>>>(
      xA0, hw0, out, NTOK, VOCABN, DIMD);
}